// Round 2
// baseline (104.464 us; speedup 1.0000x reference)
//
#include <hip/hip_runtime.h>

// SKAttention fused, MI355X — 2-kernel split.
// Shapes: x,x1 (128,512,16,16) f32; fc_w (32,512); fc_b (32);
// fcs_w (2,512,32); fcs_b (2,512). Out: 2 x (128,512,12,16) f32 concat.
//
// Math: softmax over 2 branches -> attn0 = sigmoid(l0 - l1); attn1 = 1-attn0.
// _cat drops group 0 -> image rows 0..3 of x/x1 dead. Patch p = 4g+j (g in 1..3).
// out1[b,ch,(g-1)*4+h,4j+w] = attn0(g,j,b,ch)*x[b,ch,4g+h,4j+w] + x[4g+j,ch,4g+h,4j+w]
// out2 same with x1, attn1.
//
// K1: S[(g-1),b][j][ch] = patch mean of (x+x1)  (96 MB coalesced read -> 3 MB ws)
// K2: per (g,b,128-ch chunk): load S (L2), tiny Z matvec (redundant per chunk),
//     attn, fused elementwise output (x/x1 re-read is L3-hot; writes 96 MB).

#define BS 128
#define C  512
#define D  32

__global__ __launch_bounds__(256) void skatt_means(
    const float* __restrict__ x, const float* __restrict__ x1,
    float* __restrict__ S)
{
    const int g = blockIdx.x + 1;     // group 1..3
    const int b = blockIdx.y;         // batch
    const int q = blockIdx.z;         // channel chunk (128 ch)
    const int t = threadIdx.x;
    const int j  = t & 3;
    const int cl = t >> 2;            // 0..63

    const size_t base = (size_t)b * (C * 256);
    float* Sgb = S + ((size_t)(g - 1) * BS + b) * (4 * C);

    #pragma unroll
    for (int i = 0; i < 2; ++i) {
        const int ch = q * 128 + cl + i * 64;
        const float* px = x  + base + ch * 256 + (4 * g) * 16 + j * 4;
        const float* p1 = x1 + base + ch * 256 + (4 * g) * 16 + j * 4;
        float s = 0.f;
        #pragma unroll
        for (int h = 0; h < 4; ++h) {
            float4 a  = *(const float4*)(px + h * 16);
            float4 c2 = *(const float4*)(p1 + h * 16);
            s += (a.x + c2.x) + (a.y + c2.y) + (a.z + c2.z) + (a.w + c2.w);
        }
        Sgb[j * C + ch] = s * (1.0f / 16.0f);
    }
}

__global__ __launch_bounds__(256) void skatt_out(
    const float* __restrict__ x, const float* __restrict__ x1,
    const float* __restrict__ fc_w, const float* __restrict__ fc_b,
    const float* __restrict__ fcs_w, const float* __restrict__ fcs_b,
    const float* __restrict__ S,
    float* __restrict__ out)
{
    const int g = blockIdx.x + 1;
    const int b = blockIdx.y;
    const int q = blockIdx.z;          // 128-ch chunk
    const int t = threadIdx.x;

    __shared__ float s_S[4 * C];       // [j][ch] means
    __shared__ float s_z[4][D];
    __shared__ float s_attn[128][4];   // [ch_local][j] attn0

    const float* Sgb = S + ((size_t)(g - 1) * BS + b) * (4 * C);
    #pragma unroll
    for (int i = 0; i < 2; ++i) {
        const int idx = t + i * 256;
        ((float4*)s_S)[idx] = ((const float4*)Sgb)[idx];
    }
    __syncthreads();

    // Z[j][d] = S[j][:] . fc_w[d][:] + fc_b[d]   (128 threads)
    if (t < 128) {
        const int j = t >> 5, d = t & 31;
        const float4* wrow = (const float4*)(fc_w + d * C);
        const float4* srow = (const float4*)(s_S + j * C);
        float acc = 0.f;
        #pragma unroll 4
        for (int c4 = 0; c4 < C / 4; ++c4) {
            float4 w = wrow[c4], s = srow[c4];
            acc += w.x * s.x + w.y * s.y + w.z * s.z + w.w * s.w;
        }
        s_z[j][d] = acc + fc_b[d];
    }
    __syncthreads();

    // attn0[ch_local][j] = sigmoid( Z[j] . (fcs_w0[ch]-fcs_w1[ch]) + b0-b1 )
    #pragma unroll
    for (int i = 0; i < 2; ++i) {
        const int v  = t + i * 256;
        const int cl = v >> 2, j = v & 3;
        const int ch = q * 128 + cl;
        const float4* w0 = (const float4*)(fcs_w + ch * D);
        const float4* w1 = (const float4*)(fcs_w + C * D + ch * D);
        const float4* zz = (const float4*)(&s_z[j][0]);
        float acc = fcs_b[ch] - fcs_b[C + ch];
        #pragma unroll
        for (int d4 = 0; d4 < D / 4; ++d4) {
            float4 a = w0[d4], c2 = w1[d4], z = zz[d4];
            acc += z.x * (a.x - c2.x) + z.y * (a.y - c2.y)
                 + z.z * (a.z - c2.z) + z.w * (a.w - c2.w);
        }
        s_attn[cl][j] = 1.0f / (1.0f + __expf(-acc));
    }
    __syncthreads();

    // fused elementwise output, 128 ch x 64 elems per block
    const size_t out2_off = (size_t)BS * C * 192;
    const size_t xbase = (size_t)b * (C * 256);
    float* o1 = out + (size_t)b * (C * 192) + (g - 1) * 64;
    float* o2 = o1 + out2_off;

    #pragma unroll
    for (int it = 0; it < 8; ++it) {
        const int f  = t + it * 256;   // 0..2047
        const int cl = f >> 4;
        const int h  = (f >> 2) & 3;
        const int j  = f & 3;
        const int ch = q * 128 + cl;
        const int sp = (4 * g + h) * 16 + j * 4;

        float4 a  = *(const float4*)(x  + xbase + ch * 256 + sp);
        float4 c2 = *(const float4*)(x1 + xbase + ch * 256 + sp);
        const size_t dofs = (size_t)(4 * g + j) * (C * 256) + ch * 256 + sp;
        float4 dg  = *(const float4*)(x  + dofs);
        float4 dg2 = *(const float4*)(x1 + dofs);

        const float at0 = s_attn[cl][j];
        const float at1 = 1.0f - at0;

        float4 r1, r2;
        r1.x = at0 * a.x + dg.x;   r2.x = at1 * c2.x + dg2.x;
        r1.y = at0 * a.y + dg.y;   r2.y = at1 * c2.y + dg2.y;
        r1.z = at0 * a.z + dg.z;   r2.z = at1 * c2.z + dg2.z;
        r1.w = at0 * a.w + dg.w;   r2.w = at1 * c2.w + dg2.w;

        const int oofs = ch * 192 + h * 16 + j * 4;
        *(float4*)(o1 + oofs) = r1;
        *(float4*)(o2 + oofs) = r2;
    }
}

extern "C" void kernel_launch(void* const* d_in, const int* in_sizes, int n_in,
                              void* d_out, int out_size, void* d_ws, size_t ws_size,
                              hipStream_t stream) {
    const float* x     = (const float*)d_in[0];
    const float* x1    = (const float*)d_in[1];
    const float* fc_w  = (const float*)d_in[2];
    const float* fc_b  = (const float*)d_in[3];
    const float* fcs_w = (const float*)d_in[4];
    const float* fcs_b = (const float*)d_in[5];
    float* out = (float*)d_out;
    float* S   = (float*)d_ws;        // 3*128*4*512 floats = 3 MB

    dim3 grid(3, BS, 4);
    skatt_means<<<grid, 256, 0, stream>>>(x, x1, S);
    skatt_out<<<grid, 256, 0, stream>>>(x, x1, fc_w, fc_b, fcs_w, fcs_b, S, out);
}

// Round 3
// 79.210 us; speedup vs baseline: 1.3188x; 1.3188x over previous
//
#include <hip/hip_runtime.h>

// SKAttention fused, MI355X — 4-kernel pipeline, gather-free streaming.
// x,x1 (128,512,16,16) f32; fc_w (32,512); fc_b (32); fcs_w (2,512,32); fcs_b (2,512).
// Out: 2 x (128,512,12,16) f32 concat.
//
// attn0 = sigmoid(l0-l1) (2-way softmax). Group 0 dropped -> image rows 0..3 dead.
// out1[b,ch,4(g-1)+h,4j+w] = attn0(g,j,b,ch)*x[b,ch,4g+h,4j+w] + x[4g+j,ch,4g+h,4j+w]
// out2 same with x1, 1-attn0.
//
// K1 : patch means of (x+x1) -> S[g][b][j][ch]           (96 MB stream read)
// K1b: diag extras -> E[src][ch][g1][h][j][4] (384 KB ea) laid out in OUTPUT order
// K2 : Z matvec + attn -> A[g][b][ch][j] (3 MB), once (not per ch-chunk)
// K3 : pure streaming elementwise: all loads/stores coalesced float4, no gathers.

#define BS 128
#define C  512
#define D  32

__global__ __launch_bounds__(256) void skatt_means(
    const float* __restrict__ x, const float* __restrict__ x1,
    float* __restrict__ S)
{
    const int g = blockIdx.x + 1;
    const int b = blockIdx.y;
    const int q = blockIdx.z;
    const int t = threadIdx.x;
    const int j  = t & 3;
    const int cl = t >> 2;

    const size_t base = (size_t)b * (C * 256);
    float* Sgb = S + ((size_t)(g - 1) * BS + b) * (4 * C);

    #pragma unroll
    for (int i = 0; i < 2; ++i) {
        const int ch = q * 128 + cl + i * 64;
        const float* px = x  + base + ch * 256 + (4 * g) * 16 + j * 4;
        const float* p1 = x1 + base + ch * 256 + (4 * g) * 16 + j * 4;
        float s = 0.f;
        #pragma unroll
        for (int h = 0; h < 4; ++h) {
            float4 a  = *(const float4*)(px + h * 16);
            float4 c2 = *(const float4*)(p1 + h * 16);
            s += (a.x + c2.x) + (a.y + c2.y) + (a.z + c2.z) + (a.w + c2.w);
        }
        Sgb[j * C + ch] = s * (1.0f / 16.0f);
    }
}

// E[src][ch*192 + g1*64 + h*16 + j*4 + w] = src[4(g1+1)+j][ch][4(g1+1)+h][4j+w]
__global__ __launch_bounds__(256) void skatt_diag(
    const float* __restrict__ x, const float* __restrict__ x1,
    float* __restrict__ E)  // E1 | E2, each 512*192 floats
{
    const int src = blockIdx.y;
    const float* in = src ? x1 : x;
    float* Eo = E + (size_t)src * (C * 192);

    const int flat = blockIdx.x * 256 + threadIdx.x;   // 0..24575 float4
    const int ch  = flat / 48;
    const int rem = flat - ch * 48;
    const int g   = (rem >> 4) + 1;
    const int h   = (rem >> 2) & 3;
    const int j   = rem & 3;

    const size_t src_ofs = (size_t)(4 * g + j) * (C * 256) + ch * 256 + (4 * g + h) * 16 + 4 * j;
    float4 v = *(const float4*)(in + src_ofs);
    *(float4*)(Eo + ch * 192 + rem * 4) = v;
}

__global__ __launch_bounds__(256) void skatt_attn(
    const float* __restrict__ fc_w, const float* __restrict__ fc_b,
    const float* __restrict__ fcs_w, const float* __restrict__ fcs_b,
    const float* __restrict__ S,
    float* __restrict__ A)   // A[g1][b][ch][j]
{
    const int g1 = blockIdx.x;
    const int b  = blockIdx.y;
    const int t  = threadIdx.x;

    __shared__ float s_S[4 * C];
    __shared__ float s_z[4][D];

    const float* Sgb = S + ((size_t)g1 * BS + b) * (4 * C);
    #pragma unroll
    for (int i = 0; i < 2; ++i) {
        const int idx = t + i * 256;
        ((float4*)s_S)[idx] = ((const float4*)Sgb)[idx];
    }
    __syncthreads();

    if (t < 128) {
        const int j = t >> 5, d = t & 31;
        const float4* wrow = (const float4*)(fc_w + d * C);
        const float4* srow = (const float4*)(s_S + j * C);
        float a0 = 0.f, a1 = 0.f, a2 = 0.f, a3 = 0.f;
        #pragma unroll
        for (int c4 = 0; c4 < C / 16; ++c4) {
            float4 w, s;
            w = wrow[4*c4+0]; s = srow[4*c4+0]; a0 += w.x*s.x + w.y*s.y + w.z*s.z + w.w*s.w;
            w = wrow[4*c4+1]; s = srow[4*c4+1]; a1 += w.x*s.x + w.y*s.y + w.z*s.z + w.w*s.w;
            w = wrow[4*c4+2]; s = srow[4*c4+2]; a2 += w.x*s.x + w.y*s.y + w.z*s.z + w.w*s.w;
            w = wrow[4*c4+3]; s = srow[4*c4+3]; a3 += w.x*s.x + w.y*s.y + w.z*s.z + w.w*s.w;
        }
        s_z[j][d] = (a0 + a1) + (a2 + a3) + fc_b[d];
    }
    __syncthreads();

    float* Ao = A + ((size_t)g1 * BS + b) * (C * 4);
    #pragma unroll
    for (int i = 0; i < 8; ++i) {
        const int v  = t + i * 256;     // 0..2047
        const int ch = v >> 2, j = v & 3;
        const float4* w0 = (const float4*)(fcs_w + ch * D);
        const float4* w1 = (const float4*)(fcs_w + C * D + ch * D);
        const float4* zz = (const float4*)(&s_z[j][0]);
        float acc = fcs_b[ch] - fcs_b[C + ch];
        #pragma unroll
        for (int d4 = 0; d4 < D / 4; ++d4) {
            float4 a = w0[d4], c2 = w1[d4], z = zz[d4];
            acc += z.x * (a.x - c2.x) + z.y * (a.y - c2.y)
                 + z.z * (a.z - c2.z) + z.w * (a.w - c2.w);
        }
        Ao[ch * 4 + j] = 1.0f / (1.0f + __expf(-acc));
    }
}

__global__ __launch_bounds__(256) void skatt_out(
    const float* __restrict__ x, const float* __restrict__ x1,
    const float* __restrict__ E,   // E1 | E2
    const float* __restrict__ A,   // A[g1][b][ch][j]
    float* __restrict__ out)
{
    const int q = blockIdx.x;      // 64-ch chunk (0..7)
    const int b = blockIdx.y;
    const int t = threadIdx.x;

    __shared__ float s_A[64][12];  // [ch_l][g1*4+j], row stride 48 B (16B aligned)

    // load attn slice: per g1, 256 contiguous floats at A[(g1*128+b)*2048 + q*256]
    if (t < 192) {
        const int g1 = t >> 6, r = t & 63;
        float4 v = *(const float4*)(A + ((size_t)g1 * BS + b) * (C * 4) + q * 256 + r * 4);
        *(float4*)(&s_A[r][g1 * 4]) = v;
    }
    __syncthreads();

    const size_t xbase = (size_t)b * (C * 256);
    const size_t obase = (size_t)b * (C * 192);
    const size_t out2_off = (size_t)BS * C * 192;
    const float* E1 = E;
    const float* E2 = E + (size_t)C * 192;

    #pragma unroll
    for (int i = 0; i < 12; ++i) {
        const int v    = t + i * 256;        // 0..3071 float4 index
        const int ch_l = v / 48;
        const int rem  = v - ch_l * 48;      // g1*16 + h*4 + j
        const int ch   = q * 64 + ch_l;
        const int j    = rem & 3;
        const int g1   = rem >> 4;

        const float at0 = s_A[ch_l][g1 * 4 + j];
        const float at1 = 1.0f - at0;

        const size_t xofs = xbase + ch * 256 + 64 + rem * 4;  // rows 4..16
        float4 a  = *(const float4*)(x  + xofs);
        float4 c2 = *(const float4*)(x1 + xofs);
        const size_t eofs = (size_t)ch * 192 + rem * 4;
        float4 e1 = *(const float4*)(E1 + eofs);
        float4 e2 = *(const float4*)(E2 + eofs);

        float4 r1, r2;
        r1.x = at0 * a.x + e1.x;   r2.x = at1 * c2.x + e2.x;
        r1.y = at0 * a.y + e1.y;   r2.y = at1 * c2.y + e2.y;
        r1.z = at0 * a.z + e1.z;   r2.z = at1 * c2.z + e2.z;
        r1.w = at0 * a.w + e1.w;   r2.w = at1 * c2.w + e2.w;

        const size_t oofs = obase + ch * 192 + rem * 4;
        *(float4*)(out + oofs) = r1;
        *(float4*)(out + out2_off + oofs) = r2;
    }
}

extern "C" void kernel_launch(void* const* d_in, const int* in_sizes, int n_in,
                              void* d_out, int out_size, void* d_ws, size_t ws_size,
                              hipStream_t stream) {
    const float* x     = (const float*)d_in[0];
    const float* x1    = (const float*)d_in[1];
    const float* fc_w  = (const float*)d_in[2];
    const float* fc_b  = (const float*)d_in[3];
    const float* fcs_w = (const float*)d_in[4];
    const float* fcs_b = (const float*)d_in[5];
    float* out = (float*)d_out;

    float* S = (float*)d_ws;                       // 3*128*4*512 = 3 MB
    float* A = S + (size_t)3 * BS * 4 * C;         // 3*128*512*4 = 3 MB
    float* E = A + (size_t)3 * BS * C * 4;         // 2*512*192   = 768 KB

    skatt_means<<<dim3(3, BS, 4), 256, 0, stream>>>(x, x1, S);
    skatt_diag <<<dim3(96, 2),    256, 0, stream>>>(x, x1, E);
    skatt_attn <<<dim3(3, BS),    256, 0, stream>>>(fc_w, fc_b, fcs_w, fcs_b, S, A);
    skatt_out  <<<dim3(8, BS),    256, 0, stream>>>(x, x1, E, A, out);
}

// Round 5
// 79.012 us; speedup vs baseline: 1.3221x; 1.0025x over previous
//
#include <hip/hip_runtime.h>

// SKAttention fused, MI355X — 3-kernel pipeline.
// x,x1 (128,512,16,16) f32; fc_w (32,512); fc_b (32); fcs_w (2,512,32); fcs_b (2,512).
// Out: 2 x (128,512,12,16) f32 concat.
//
// attn0 = sigmoid(l0-l1) (2-way softmax). Group 0 dropped -> image rows 0..3 dead.
// out1[b,ch,4(g-1)+h,4j+w] = attn0(g,j,b,ch)*x[b,ch,4g+h,4j+w] + x[4g+j,ch,4g+h,4j+w]
// out2 same with x1, 1-attn0.
//
// K1 (mattn): per (g,b): patch means of (x+x1) -> Z matvec -> attn -> A[g][b][ch][j]
// K2 (diag):  diag extras -> E[src][ch][g1][h][j][4], laid out in OUTPUT order
// K3 (out):   pure streaming elementwise; nontemporal stores (out never re-read,
//             keeps x/x1 L3-resident); 2048 blocks for TLP.

#define BS 128
#define C  512
#define D  32
#define QCH 32   // channels per K3 block

typedef float f32x4 __attribute__((ext_vector_type(4)));

__global__ __launch_bounds__(512) void skatt_mattn(
    const float* __restrict__ x, const float* __restrict__ x1,
    const float* __restrict__ fc_w, const float* __restrict__ fc_b,
    const float* __restrict__ fcs_w, const float* __restrict__ fcs_b,
    float* __restrict__ A)   // A[g1][b][ch][j]
{
    const int g = blockIdx.x + 1;
    const int b = blockIdx.y;
    const int t = threadIdx.x;

    __shared__ float s_mean[4][C];
    __shared__ float s_z[4][D];

    const float* xb  = x  + (size_t)b * (C * 256) + g * 64;
    const float* x1b = x1 + (size_t)b * (C * 256) + g * 64;

    // patch means of (x + x1)
    {
        const int j   = t & 3;
        const int chb = t >> 2;
        #pragma unroll
        for (int it = 0; it < 4; ++it) {
            const int ch = chb + 128 * it;
            const float* px = xb  + ch * 256 + j * 4;
            const float* p1 = x1b + ch * 256 + j * 4;
            float s = 0.f;
            #pragma unroll
            for (int h = 0; h < 4; ++h) {
                float4 a  = *(const float4*)(px + h * 16);
                float4 c2 = *(const float4*)(p1 + h * 16);
                s += (a.x + c2.x) + (a.y + c2.y) + (a.z + c2.z) + (a.w + c2.w);
            }
            s_mean[j][ch] = s * (1.0f / 16.0f);
        }
    }
    __syncthreads();

    // Z[j][d]
    if (t < 128) {
        const int j = t >> 5, d = t & 31;
        const float4* wrow = (const float4*)(fc_w + d * C);
        const float4* srow = (const float4*)(&s_mean[j][0]);
        float a0 = 0.f, a1 = 0.f, a2 = 0.f, a3 = 0.f;
        #pragma unroll
        for (int c4 = 0; c4 < C / 16; ++c4) {
            float4 w, s;
            w = wrow[4*c4+0]; s = srow[4*c4+0]; a0 += w.x*s.x + w.y*s.y + w.z*s.z + w.w*s.w;
            w = wrow[4*c4+1]; s = srow[4*c4+1]; a1 += w.x*s.x + w.y*s.y + w.z*s.z + w.w*s.w;
            w = wrow[4*c4+2]; s = srow[4*c4+2]; a2 += w.x*s.x + w.y*s.y + w.z*s.z + w.w*s.w;
            w = wrow[4*c4+3]; s = srow[4*c4+3]; a3 += w.x*s.x + w.y*s.y + w.z*s.z + w.w*s.w;
        }
        s_z[j][d] = (a0 + a1) + (a2 + a3) + fc_b[d];
    }
    __syncthreads();

    // attn0 -> A
    float* Ao = A + ((size_t)(g - 1) * BS + b) * (C * 4);
    #pragma unroll
    for (int i = 0; i < 4; ++i) {
        const int v  = t + i * 512;     // 0..2047
        const int ch = v >> 2, j = v & 3;
        const float4* w0 = (const float4*)(fcs_w + ch * D);
        const float4* w1 = (const float4*)(fcs_w + C * D + ch * D);
        const float4* zz = (const float4*)(&s_z[j][0]);
        float acc = fcs_b[ch] - fcs_b[C + ch];
        #pragma unroll
        for (int d4 = 0; d4 < D / 4; ++d4) {
            float4 a = w0[d4], c2 = w1[d4], z = zz[d4];
            acc += z.x * (a.x - c2.x) + z.y * (a.y - c2.y)
                 + z.z * (a.z - c2.z) + z.w * (a.w - c2.w);
        }
        Ao[v] = 1.0f / (1.0f + __expf(-acc));
    }
}

// E[src][ch*192 + (g-1)*64 + h*16 + j*4 + w] = src[4g+j][ch][4g+h][4j+w]
__global__ __launch_bounds__(256) void skatt_diag(
    const float* __restrict__ x, const float* __restrict__ x1,
    float* __restrict__ E)
{
    const int src = blockIdx.y;
    const float* in = src ? x1 : x;
    float* Eo = E + (size_t)src * (C * 192);

    const int flat = blockIdx.x * 256 + threadIdx.x;   // 0..24575 float4
    const int ch  = flat / 48;
    const int rem = flat - ch * 48;
    const int g   = (rem >> 4) + 1;
    const int h   = (rem >> 2) & 3;
    const int j   = rem & 3;

    const size_t src_ofs = (size_t)(4 * g + j) * (C * 256) + ch * 256 + (4 * g + h) * 16 + 4 * j;
    float4 v = *(const float4*)(in + src_ofs);
    *(float4*)(Eo + ch * 192 + rem * 4) = v;
}

__global__ __launch_bounds__(256) void skatt_out(
    const float* __restrict__ x, const float* __restrict__ x1,
    const float* __restrict__ E,
    const float* __restrict__ A,
    float* __restrict__ out)
{
    const int q = blockIdx.x;      // 32-ch chunk (0..15)
    const int b = blockIdx.y;
    const int t = threadIdx.x;

    __shared__ float s_A[QCH][12];  // [ch_l][g1*4+j]

    if (t < 96) {
        const int g1 = t >> 5, r = t & 31;
        float4 v = *(const float4*)(A + ((size_t)g1 * BS + b) * (C * 4) + q * (QCH * 4) + r * 4);
        *(float4*)(&s_A[r][g1 * 4]) = v;
    }
    __syncthreads();

    const size_t xbase = (size_t)b * (C * 256);
    const size_t obase = (size_t)b * (C * 192);
    const size_t out2_off = (size_t)BS * C * 192;
    const float* E1 = E;
    const float* E2 = E + (size_t)C * 192;

    #pragma unroll
    for (int i = 0; i < 6; ++i) {
        const int v    = t + i * 256;        // 0..1535 float4 index
        const int ch_l = v / 48;             // 0..31
        const int rem  = v - ch_l * 48;      // g1*16 + h*4 + j
        const int ch   = q * QCH + ch_l;
        const int j    = rem & 3;
        const int g1   = rem >> 4;

        const float at0 = s_A[ch_l][g1 * 4 + j];
        const float at1 = 1.0f - at0;

        const size_t xofs = xbase + ch * 256 + 64 + rem * 4;
        float4 a  = *(const float4*)(x  + xofs);
        float4 c2 = *(const float4*)(x1 + xofs);
        const size_t eofs = (size_t)ch * 192 + rem * 4;
        float4 e1 = *(const float4*)(E1 + eofs);
        float4 e2 = *(const float4*)(E2 + eofs);

        f32x4 r1, r2;
        r1.x = at0 * a.x + e1.x;   r2.x = at1 * c2.x + e2.x;
        r1.y = at0 * a.y + e1.y;   r2.y = at1 * c2.y + e2.y;
        r1.z = at0 * a.z + e1.z;   r2.z = at1 * c2.z + e2.z;
        r1.w = at0 * a.w + e1.w;   r2.w = at1 * c2.w + e2.w;

        const size_t oofs = obase + ch * 192 + rem * 4;
        __builtin_nontemporal_store(r1, (f32x4*)(out + oofs));
        __builtin_nontemporal_store(r2, (f32x4*)(out + out2_off + oofs));
    }
}

extern "C" void kernel_launch(void* const* d_in, const int* in_sizes, int n_in,
                              void* d_out, int out_size, void* d_ws, size_t ws_size,
                              hipStream_t stream) {
    const float* x     = (const float*)d_in[0];
    const float* x1    = (const float*)d_in[1];
    const float* fc_w  = (const float*)d_in[2];
    const float* fc_b  = (const float*)d_in[3];
    const float* fcs_w = (const float*)d_in[4];
    const float* fcs_b = (const float*)d_in[5];
    float* out = (float*)d_out;

    float* A = (float*)d_ws;                       // 3*128*512*4 = 3 MB
    float* E = A + (size_t)3 * BS * C * 4;         // 2*512*192   = 768 KB

    skatt_diag <<<dim3(96, 2),     256, 0, stream>>>(x, x1, E);
    skatt_mattn<<<dim3(3, BS),     512, 0, stream>>>(x, x1, fc_w, fc_b, fcs_w, fcs_b, A);
    skatt_out  <<<dim3(16, BS),    256, 0, stream>>>(x, x1, E, A, out);
}

// Round 6
// 78.527 us; speedup vs baseline: 1.3303x; 1.0062x over previous
//
#include <hip/hip_runtime.h>

// SKAttention fused, MI355X — 3-kernel pipeline (split means / attn / out).
// x,x1 (128,512,16,16) f32; fc_w (32,512); fc_b (32); fcs_w (2,512,32); fcs_b (2,512).
// Out: 2 x (128,512,12,16) f32 concat.
//
// attn0 = sigmoid(l0-l1) (2-way softmax). Group 0 dropped -> image rows 0..3 dead.
// out1[b,ch,4(g-1)+h,4j+w] = attn0(g,j,b,ch)*x[b,ch,4g+h,4j+w] + x[4g+j,ch,4g+h,4j+w]
// out2 same with x1, 1-attn0.
//
// K1 (means): 1536 blocks, no LDS, per-thread patch sums -> S[g][b][j][ch].
//             Diag extras folded in: blocks with b==4g+j write E (1/4 lanes, 12 blocks).
// K2 (attn):  per (g,b): S -> Z matvec -> attn0 -> A[g][b][ch][j].
// K3 (out):   pure streaming elementwise, nontemporal stores, 2048 blocks.

#define BS 128
#define C  512
#define D  32
#define QCH 32   // channels per K3 block

typedef float f32x4 __attribute__((ext_vector_type(4)));

__global__ __launch_bounds__(256) void skatt_means(
    const float* __restrict__ x, const float* __restrict__ x1,
    float* __restrict__ S,    // S[g1][b][j][ch]
    float* __restrict__ E)    // E1 | E2, each [ch][g1*64 + h*16 + j*4 + w]
{
    const int g = blockIdx.x + 1;     // 1..3
    const int b = blockIdx.y;
    const int q = blockIdx.z;         // 128-ch chunk
    const int t = threadIdx.x;
    const int j  = t & 3;
    const int cl = t >> 2;            // 0..63

    const size_t base = (size_t)b * (C * 256);
    float* Sgb = S + ((size_t)(g - 1) * BS + b) * (4 * C);
    const bool diag = (b == 4 * g + j);
    float* E1 = E;
    float* E2 = E + (size_t)C * 192;

    #pragma unroll
    for (int i = 0; i < 2; ++i) {
        const int ch = q * 128 + cl + i * 64;
        const float* px = x  + base + ch * 256 + (4 * g) * 16 + j * 4;
        const float* p1 = x1 + base + ch * 256 + (4 * g) * 16 + j * 4;
        float s = 0.f;
        #pragma unroll
        for (int h = 0; h < 4; ++h) {
            float4 a  = *(const float4*)(px + h * 16);
            float4 c2 = *(const float4*)(p1 + h * 16);
            s += (a.x + c2.x) + (a.y + c2.y) + (a.z + c2.z) + (a.w + c2.w);
            if (diag) {
                const size_t eofs = (size_t)ch * 192 + (g - 1) * 64 + h * 16 + j * 4;
                *(float4*)(E1 + eofs) = a;
                *(float4*)(E2 + eofs) = c2;
            }
        }
        Sgb[j * C + ch] = s * (1.0f / 16.0f);
    }
}

__global__ __launch_bounds__(256) void skatt_attn(
    const float* __restrict__ fc_w, const float* __restrict__ fc_b,
    const float* __restrict__ fcs_w, const float* __restrict__ fcs_b,
    const float* __restrict__ S,
    float* __restrict__ A)   // A[g1][b][ch][j]
{
    const int g1 = blockIdx.x;
    const int b  = blockIdx.y;
    const int t  = threadIdx.x;

    __shared__ float s_S[4 * C];
    __shared__ float s_z[4][D];

    const float* Sgb = S + ((size_t)g1 * BS + b) * (4 * C);
    #pragma unroll
    for (int i = 0; i < 2; ++i) {
        const int idx = t + i * 256;
        ((float4*)s_S)[idx] = ((const float4*)Sgb)[idx];
    }
    __syncthreads();

    if (t < 128) {
        const int j = t >> 5, d = t & 31;
        const float4* wrow = (const float4*)(fc_w + d * C);
        const float4* srow = (const float4*)(s_S + j * C);
        float a0 = 0.f, a1 = 0.f, a2 = 0.f, a3 = 0.f;
        #pragma unroll
        for (int c4 = 0; c4 < C / 16; ++c4) {
            float4 w, s;
            w = wrow[4*c4+0]; s = srow[4*c4+0]; a0 += w.x*s.x + w.y*s.y + w.z*s.z + w.w*s.w;
            w = wrow[4*c4+1]; s = srow[4*c4+1]; a1 += w.x*s.x + w.y*s.y + w.z*s.z + w.w*s.w;
            w = wrow[4*c4+2]; s = srow[4*c4+2]; a2 += w.x*s.x + w.y*s.y + w.z*s.z + w.w*s.w;
            w = wrow[4*c4+3]; s = srow[4*c4+3]; a3 += w.x*s.x + w.y*s.y + w.z*s.z + w.w*s.w;
        }
        s_z[j][d] = (a0 + a1) + (a2 + a3) + fc_b[d];
    }
    __syncthreads();

    float* Ao = A + ((size_t)g1 * BS + b) * (C * 4);
    #pragma unroll
    for (int i = 0; i < 8; ++i) {
        const int v  = t + i * 256;     // 0..2047
        const int ch = v >> 2, j = v & 3;
        const float4* w0 = (const float4*)(fcs_w + ch * D);
        const float4* w1 = (const float4*)(fcs_w + C * D + ch * D);
        const float4* zz = (const float4*)(&s_z[j][0]);
        float acc = fcs_b[ch] - fcs_b[C + ch];
        #pragma unroll
        for (int d4 = 0; d4 < D / 4; ++d4) {
            float4 a = w0[d4], c2 = w1[d4], z = zz[d4];
            acc += z.x * (a.x - c2.x) + z.y * (a.y - c2.y)
                 + z.z * (a.z - c2.z) + z.w * (a.w - c2.w);
        }
        Ao[v] = 1.0f / (1.0f + __expf(-acc));
    }
}

__global__ __launch_bounds__(256) void skatt_out(
    const float* __restrict__ x, const float* __restrict__ x1,
    const float* __restrict__ E,
    const float* __restrict__ A,
    float* __restrict__ out)
{
    const int q = blockIdx.x;      // 32-ch chunk (0..15)
    const int b = blockIdx.y;
    const int t = threadIdx.x;

    __shared__ float s_A[QCH][12];  // [ch_l][g1*4+j]

    if (t < 96) {
        const int g1 = t >> 5, r = t & 31;
        float4 v = *(const float4*)(A + ((size_t)g1 * BS + b) * (C * 4) + q * (QCH * 4) + r * 4);
        *(float4*)(&s_A[r][g1 * 4]) = v;
    }
    __syncthreads();

    const size_t xbase = (size_t)b * (C * 256);
    const size_t obase = (size_t)b * (C * 192);
    const size_t out2_off = (size_t)BS * C * 192;
    const float* E1 = E;
    const float* E2 = E + (size_t)C * 192;

    #pragma unroll
    for (int i = 0; i < 6; ++i) {
        const int v    = t + i * 256;        // 0..1535 float4 index
        const int ch_l = v / 48;             // 0..31
        const int rem  = v - ch_l * 48;      // g1*16 + h*4 + j
        const int ch   = q * QCH + ch_l;
        const int j    = rem & 3;
        const int g1   = rem >> 4;

        const float at0 = s_A[ch_l][g1 * 4 + j];
        const float at1 = 1.0f - at0;

        const size_t xofs = xbase + ch * 256 + 64 + rem * 4;
        float4 a  = *(const float4*)(x  + xofs);
        float4 c2 = *(const float4*)(x1 + xofs);
        const size_t eofs = (size_t)ch * 192 + rem * 4;
        float4 e1 = *(const float4*)(E1 + eofs);
        float4 e2 = *(const float4*)(E2 + eofs);

        f32x4 r1, r2;
        r1.x = at0 * a.x + e1.x;   r2.x = at1 * c2.x + e2.x;
        r1.y = at0 * a.y + e1.y;   r2.y = at1 * c2.y + e2.y;
        r1.z = at0 * a.z + e1.z;   r2.z = at1 * c2.z + e2.z;
        r1.w = at0 * a.w + e1.w;   r2.w = at1 * c2.w + e2.w;

        const size_t oofs = obase + ch * 192 + rem * 4;
        __builtin_nontemporal_store(r1, (f32x4*)(out + oofs));
        __builtin_nontemporal_store(r2, (f32x4*)(out + out2_off + oofs));
    }
}

extern "C" void kernel_launch(void* const* d_in, const int* in_sizes, int n_in,
                              void* d_out, int out_size, void* d_ws, size_t ws_size,
                              hipStream_t stream) {
    const float* x     = (const float*)d_in[0];
    const float* x1    = (const float*)d_in[1];
    const float* fc_w  = (const float*)d_in[2];
    const float* fc_b  = (const float*)d_in[3];
    const float* fcs_w = (const float*)d_in[4];
    const float* fcs_b = (const float*)d_in[5];
    float* out = (float*)d_out;

    float* S = (float*)d_ws;                       // 3*128*4*512 = 3 MB
    float* A = S + (size_t)3 * BS * 4 * C;         // 3 MB
    float* E = A + (size_t)3 * BS * C * 4;         // 768 KB

    skatt_means<<<dim3(3, BS, 4), 256, 0, stream>>>(x, x1, S, E);
    skatt_attn <<<dim3(3, BS),    256, 0, stream>>>(fc_w, fc_b, fcs_w, fcs_b, S, A);
    skatt_out  <<<dim3(16, BS),   256, 0, stream>>>(x, x1, E, A, out);
}

// Round 7
// 75.355 us; speedup vs baseline: 1.3863x; 1.0421x over previous
//
#include <hip/hip_runtime.h>

// SKAttention fused, MI355X — 5-kernel pipeline, zero gathered weight loads.
// x,x1 (128,512,16,16) f32; fc_w (32,512); fc_b (32); fcs_w (2,512,32); fcs_b (2,512).
// Out: 2 x (128,512,12,16) f32 concat.
//
// attn0 = sigmoid(l0-l1). Group 0 dropped -> rows 0..3 dead. p = 4g+j, g in 1..3.
// out1[b,ch,4(g-1)+h,4j+w] = attn0(g,j,b,ch)*x[b,ch,4g+h,4j+w] + x[4g+j,ch,4g+h,4j+w]
// out2 same with x1, 1-attn0.
//
// Lesson from rounds 2/5/6: any phase reading weights with lane-varying row
// addresses (fc_w[d][c], fcs_w[ch][d]) runs at latency, not BW (45-90 us).
// Fix: transpose weights once (K0) so all weight loads are coalesced lines.

#define BS 128
#define C  512
#define D  32
#define QCH 32

typedef float f32x4 __attribute__((ext_vector_type(4)));

// K0: fc_wT[c][d] = fc_w[d][c]; Wd[ch][d] = fcs_w0[ch][d]-fcs_w1[ch][d]; bd = b0-b1.
__global__ __launch_bounds__(256) void skatt_wprep(
    const float* __restrict__ fc_w, const float* __restrict__ fcs_w,
    const float* __restrict__ fcs_b,
    float* __restrict__ fc_wT, float* __restrict__ Wd, float* __restrict__ bd)
{
    const int i = blockIdx.x * 256 + threadIdx.x;   // 0..4095 (float4 index)
    {   // transpose: out float4 covers fc_wT[c][d0..d0+3]
        const int c = i >> 3, d0 = (i & 7) * 4;
        f32x4 v;
        v.x = fc_w[(d0 + 0) * C + c];
        v.y = fc_w[(d0 + 1) * C + c];
        v.z = fc_w[(d0 + 2) * C + c];
        v.w = fc_w[(d0 + 3) * C + c];
        *(f32x4*)(fc_wT + i * 4) = v;
    }
    {   // Wd (coalesced in, coalesced out)
        float4 a = *(const float4*)(fcs_w + (size_t)i * 4);
        float4 b = *(const float4*)(fcs_w + (size_t)C * D + (size_t)i * 4);
        f32x4 r;
        r.x = a.x - b.x; r.y = a.y - b.y; r.z = a.z - b.z; r.w = a.w - b.w;
        *(f32x4*)(Wd + i * 4) = r;
    }
    if (i < 128) {
        float4 a = *(const float4*)(fcs_b + i * 4);
        float4 b = *(const float4*)(fcs_b + C + i * 4);
        f32x4 r;
        r.x = a.x - b.x; r.y = a.y - b.y; r.z = a.z - b.z; r.w = a.w - b.w;
        *(f32x4*)(bd + i * 4) = r;
    }
}

// K1: patch means of (x+x1) -> S[g1][b][j][ch]; diag extras folded in.
__global__ __launch_bounds__(256) void skatt_means(
    const float* __restrict__ x, const float* __restrict__ x1,
    float* __restrict__ S, float* __restrict__ E)
{
    const int g = blockIdx.x + 1;
    const int b = blockIdx.y;
    const int q = blockIdx.z;
    const int t = threadIdx.x;
    const int j  = t & 3;
    const int cl = t >> 2;

    const size_t base = (size_t)b * (C * 256);
    float* Sgb = S + ((size_t)(g - 1) * BS + b) * (4 * C);
    const bool diag = (b == 4 * g + j);
    float* E1 = E;
    float* E2 = E + (size_t)C * 192;

    #pragma unroll
    for (int i = 0; i < 2; ++i) {
        const int ch = q * 128 + cl + i * 64;
        const float* px = x  + base + ch * 256 + (4 * g) * 16 + j * 4;
        const float* p1 = x1 + base + ch * 256 + (4 * g) * 16 + j * 4;
        float s = 0.f;
        #pragma unroll
        for (int h = 0; h < 4; ++h) {
            float4 a  = *(const float4*)(px + h * 16);
            float4 c2 = *(const float4*)(p1 + h * 16);
            s += (a.x + c2.x) + (a.y + c2.y) + (a.z + c2.z) + (a.w + c2.w);
            if (diag) {
                const size_t eofs = (size_t)ch * 192 + (g - 1) * 64 + h * 16 + j * 4;
                *(float4*)(E1 + eofs) = a;
                *(float4*)(E2 + eofs) = c2;
            }
        }
        Sgb[j * C + ch] = s * (1.0f / 16.0f);
    }
}

// K2: Z[g1][b][j][d] = sum_c S[g1][b][j][c] * fc_wT[c][d] + fc_b[d]
// Lanes indexed by d -> fc_wT row reads are single 128B coalesced lines.
__global__ __launch_bounds__(128) void skatt_z(
    const float* __restrict__ S, const float* __restrict__ fc_wT,
    const float* __restrict__ fc_b, float* __restrict__ Z)
{
    const int g1 = blockIdx.x, b = blockIdx.y;
    const int t = threadIdx.x;     // 128
    const int j = t >> 5, d = t & 31;

    const float* Srow = S + ((size_t)g1 * BS + b) * (4 * C) + j * C;
    float a0 = 0.f, a1 = 0.f, a2 = 0.f, a3 = 0.f;
    float a4 = 0.f, a5 = 0.f, a6 = 0.f, a7 = 0.f;
    #pragma unroll 4
    for (int c8 = 0; c8 < C / 8; ++c8) {
        float4 s0 = *(const float4*)(Srow + c8 * 8);
        float4 s1 = *(const float4*)(Srow + c8 * 8 + 4);
        const float* w = fc_wT + (c8 * 8) * D + d;
        a0 += s0.x * w[0 * D]; a1 += s0.y * w[1 * D];
        a2 += s0.z * w[2 * D]; a3 += s0.w * w[3 * D];
        a4 += s1.x * w[4 * D]; a5 += s1.y * w[5 * D];
        a6 += s1.z * w[6 * D]; a7 += s1.w * w[7 * D];
    }
    Z[((size_t)(g1 * BS + b) * 4 + j) * D + d] =
        ((a0 + a1) + (a2 + a3)) + ((a4 + a5) + (a6 + a7)) + fc_b[d];
}

// K3: attn0 = sigmoid(bd[ch] + Z[g,b,j,:] . Wd[ch,:]) -> A[g1][b][ch][j]
// All operands LDS-staged; Wd transposed in LDS so reads are conflict-free.
__global__ __launch_bounds__(256) void skatt_attn2(
    const float* __restrict__ Z, const float* __restrict__ Wd,
    const float* __restrict__ bd, float* __restrict__ A)
{
    const int qc = blockIdx.x;     // 16 ch-chunks of 32
    const int qb = blockIdx.y;     // 4 b-chunks of 32
    const int g1 = blockIdx.z;
    const int t  = threadIdx.x;
    const int ch0 = qc * 32, b0 = qb * 32;

    __shared__ float s_z[32 * 4 * 32];   // [b_l][j][d] 16 KB
    __shared__ float s_wt[32][32];       // [d][ch_l]   4 KB
    __shared__ float s_bd[32];

    const float* Zs = Z + (size_t)(g1 * BS + b0) * 4 * D;
    #pragma unroll
    for (int i = 0; i < 4; ++i)
        ((float4*)s_z)[t + i * 256] = ((const float4*)Zs)[t + i * 256];
    {
        float4 v = ((const float4*)(Wd + ch0 * D))[t];
        const int ch = t >> 3, d0 = (t & 7) * 4;
        s_wt[d0 + 0][ch] = v.x; s_wt[d0 + 1][ch] = v.y;
        s_wt[d0 + 2][ch] = v.z; s_wt[d0 + 3][ch] = v.w;
    }
    if (t < 32) s_bd[t] = bd[ch0 + t];
    __syncthreads();

    const int ch_l = t & 31, bq = t >> 5;
    float wd[D];
    #pragma unroll
    for (int d = 0; d < D; ++d) wd[d] = s_wt[d][ch_l];   // lane=bank, conflict-free
    const float bdv = s_bd[ch_l];

    #pragma unroll
    for (int bi = 0; bi < 4; ++bi) {
        const int b_l = bq + 8 * bi;
        const float* zr = s_z + b_l * 128;               // broadcast reads
        f32x4 o;
        #pragma unroll
        for (int j = 0; j < 4; ++j) {
            float acc = bdv;
            #pragma unroll
            for (int d = 0; d < D; ++d) acc += zr[j * 32 + d] * wd[d];
            o[j] = 1.0f / (1.0f + __expf(-acc));
        }
        *(f32x4*)(A + ((size_t)(g1 * BS + b0 + b_l) * C + ch0 + ch_l) * 4) = o;
    }
}

// K4: streaming elementwise output, NT stores.
__global__ __launch_bounds__(256) void skatt_out(
    const float* __restrict__ x, const float* __restrict__ x1,
    const float* __restrict__ E, const float* __restrict__ A,
    float* __restrict__ out)
{
    const int q = blockIdx.x;      // 32-ch chunk
    const int b = blockIdx.y;
    const int t = threadIdx.x;

    __shared__ float s_A[QCH][12];

    if (t < 96) {
        const int g1 = t >> 5, r = t & 31;
        float4 v = *(const float4*)(A + ((size_t)g1 * BS + b) * (C * 4) + q * (QCH * 4) + r * 4);
        *(float4*)(&s_A[r][g1 * 4]) = v;
    }
    __syncthreads();

    const size_t xbase = (size_t)b * (C * 256);
    const size_t obase = (size_t)b * (C * 192);
    const size_t out2_off = (size_t)BS * C * 192;
    const float* E1 = E;
    const float* E2 = E + (size_t)C * 192;

    #pragma unroll
    for (int i = 0; i < 6; ++i) {
        const int v    = t + i * 256;
        const int ch_l = v / 48;
        const int rem  = v - ch_l * 48;
        const int ch   = q * QCH + ch_l;
        const int j    = rem & 3;
        const int g1   = rem >> 4;

        const float at0 = s_A[ch_l][g1 * 4 + j];
        const float at1 = 1.0f - at0;

        const size_t xofs = xbase + ch * 256 + 64 + rem * 4;
        float4 a  = *(const float4*)(x  + xofs);
        float4 c2 = *(const float4*)(x1 + xofs);
        const size_t eofs = (size_t)ch * 192 + rem * 4;
        float4 e1 = *(const float4*)(E1 + eofs);
        float4 e2 = *(const float4*)(E2 + eofs);

        f32x4 r1, r2;
        r1.x = at0 * a.x + e1.x;   r2.x = at1 * c2.x + e2.x;
        r1.y = at0 * a.y + e1.y;   r2.y = at1 * c2.y + e2.y;
        r1.z = at0 * a.z + e1.z;   r2.z = at1 * c2.z + e2.z;
        r1.w = at0 * a.w + e1.w;   r2.w = at1 * c2.w + e2.w;

        const size_t oofs = obase + ch * 192 + rem * 4;
        __builtin_nontemporal_store(r1, (f32x4*)(out + oofs));
        __builtin_nontemporal_store(r2, (f32x4*)(out + out2_off + oofs));
    }
}

extern "C" void kernel_launch(void* const* d_in, const int* in_sizes, int n_in,
                              void* d_out, int out_size, void* d_ws, size_t ws_size,
                              hipStream_t stream) {
    const float* x     = (const float*)d_in[0];
    const float* x1    = (const float*)d_in[1];
    const float* fc_w  = (const float*)d_in[2];
    const float* fc_b  = (const float*)d_in[3];
    const float* fcs_w = (const float*)d_in[4];
    const float* fcs_b = (const float*)d_in[5];
    float* out = (float*)d_out;

    float* S     = (float*)d_ws;            // 3*128*4*512 = 786432 f
    float* A     = S + 786432;              // 786432 f
    float* E     = A + 786432;              // 196608 f
    float* Zb    = E + 196608;              // 49152 f
    float* fc_wT = Zb + 49152;              // 16384 f
    float* Wd    = fc_wT + 16384;           // 16384 f
    float* bd    = Wd + 16384;              // 512 f

    skatt_wprep<<<16,             256, 0, stream>>>(fc_w, fcs_w, fcs_b, fc_wT, Wd, bd);
    skatt_means<<<dim3(3, BS, 4), 256, 0, stream>>>(x, x1, S, E);
    skatt_z    <<<dim3(3, BS),    128, 0, stream>>>(S, fc_wT, fc_b, Zb);
    skatt_attn2<<<dim3(16, 4, 3), 256, 0, stream>>>(Zb, Wd, bd, A);
    skatt_out  <<<dim3(16, BS),   256, 0, stream>>>(x, x1, E, A, out);
}

// Round 8
// 74.707 us; speedup vs baseline: 1.3983x; 1.0087x over previous
//
#include <hip/hip_runtime.h>

// SKAttention fused, MI355X — 6-kernel pipeline.
// x,x1 (128,512,16,16) f32; fc_w (32,512); fc_b (32); fcs_w (2,512,32); fcs_b (2,512).
// Out: 2 x (128,512,12,16) f32 concat.
//
// attn0 = sigmoid(l0-l1). Group 0 dropped -> rows 0..3 dead. p = 4g+j, g in 1..3.
// out1[b,ch,4(g-1)+h,4j+w] = attn0(g,j,b,ch)*x[b,ch,4g+h,4j+w] + x[4g+j,ch,4g+h,4j+w]
// out2 same with x1, 1-attn0.
//
// Cross-round attribution (r2..r7): means-clean=17us, out-NT=13us, diag=1.5us,
// transposed middle (wprep+z+attn2)=~4us, gathered attn=47us, means+diag-fold=60us.
// Lesson: lane-divergent predicated stores inside the streaming loop destroy
// load batching -> keep the big streaming kernel branch-free; diag is separate.

#define BS 128
#define C  512
#define D  32
#define QCH 32

typedef float f32x4 __attribute__((ext_vector_type(4)));

// K0: fc_wT[c][d] = fc_w[d][c]; Wd[ch][d] = fcs_w0[ch][d]-fcs_w1[ch][d]; bd = b0-b1.
__global__ __launch_bounds__(256) void skatt_wprep(
    const float* __restrict__ fc_w, const float* __restrict__ fcs_w,
    const float* __restrict__ fcs_b,
    float* __restrict__ fc_wT, float* __restrict__ Wd, float* __restrict__ bd)
{
    const int i = blockIdx.x * 256 + threadIdx.x;   // 0..4095 (float4 index)
    {
        const int c = i >> 3, d0 = (i & 7) * 4;
        f32x4 v;
        v.x = fc_w[(d0 + 0) * C + c];
        v.y = fc_w[(d0 + 1) * C + c];
        v.z = fc_w[(d0 + 2) * C + c];
        v.w = fc_w[(d0 + 3) * C + c];
        *(f32x4*)(fc_wT + i * 4) = v;
    }
    {
        float4 a = *(const float4*)(fcs_w + (size_t)i * 4);
        float4 b = *(const float4*)(fcs_w + (size_t)C * D + (size_t)i * 4);
        f32x4 r;
        r.x = a.x - b.x; r.y = a.y - b.y; r.z = a.z - b.z; r.w = a.w - b.w;
        *(f32x4*)(Wd + i * 4) = r;
    }
    if (i < 128) {
        float4 a = *(const float4*)(fcs_b + i * 4);
        float4 b = *(const float4*)(fcs_b + C + i * 4);
        f32x4 r;
        r.x = a.x - b.x; r.y = a.y - b.y; r.z = a.z - b.z; r.w = a.w - b.w;
        *(f32x4*)(bd + i * 4) = r;
    }
}

// K1: diag extras -> E[src][ch*192 + (g-1)*64 + h*16 + j*4 + w] = src[4g+j][ch][4g+h][4j+w]
__global__ __launch_bounds__(256) void skatt_diag(
    const float* __restrict__ x, const float* __restrict__ x1,
    float* __restrict__ E)
{
    const int src = blockIdx.y;
    const float* in = src ? x1 : x;
    float* Eo = E + (size_t)src * (C * 192);

    const int flat = blockIdx.x * 256 + threadIdx.x;   // 0..24575 float4
    const int ch  = flat / 48;
    const int rem = flat - ch * 48;
    const int g   = (rem >> 4) + 1;
    const int h   = (rem >> 2) & 3;
    const int j   = rem & 3;

    const size_t src_ofs = (size_t)(4 * g + j) * (C * 256) + ch * 256 + (4 * g + h) * 16 + 4 * j;
    float4 v = *(const float4*)(in + src_ofs);
    *(float4*)(Eo + ch * 192 + rem * 4) = v;
}

// K2: patch means of (x+x1) -> S[g1][b][j][ch]. Branch-free streaming.
__global__ __launch_bounds__(256) void skatt_means(
    const float* __restrict__ x, const float* __restrict__ x1,
    float* __restrict__ S)
{
    const int g = blockIdx.x + 1;
    const int b = blockIdx.y;
    const int q = blockIdx.z;
    const int t = threadIdx.x;
    const int j  = t & 3;
    const int cl = t >> 2;

    const size_t base = (size_t)b * (C * 256);
    float* Sgb = S + ((size_t)(g - 1) * BS + b) * (4 * C);

    #pragma unroll
    for (int i = 0; i < 2; ++i) {
        const int ch = q * 128 + cl + i * 64;
        const float* px = x  + base + ch * 256 + (4 * g) * 16 + j * 4;
        const float* p1 = x1 + base + ch * 256 + (4 * g) * 16 + j * 4;
        float s = 0.f;
        #pragma unroll
        for (int h = 0; h < 4; ++h) {
            float4 a  = *(const float4*)(px + h * 16);
            float4 c2 = *(const float4*)(p1 + h * 16);
            s += (a.x + c2.x) + (a.y + c2.y) + (a.z + c2.z) + (a.w + c2.w);
        }
        Sgb[j * C + ch] = s * (1.0f / 16.0f);
    }
}

// K3: Z[g1][b][j][d] = sum_c S[g1][b][j][c] * fc_wT[c][d] + fc_b[d]
__global__ __launch_bounds__(128) void skatt_z(
    const float* __restrict__ S, const float* __restrict__ fc_wT,
    const float* __restrict__ fc_b, float* __restrict__ Z)
{
    const int g1 = blockIdx.x, b = blockIdx.y;
    const int t = threadIdx.x;
    const int j = t >> 5, d = t & 31;

    const float* Srow = S + ((size_t)g1 * BS + b) * (4 * C) + j * C;
    float a0 = 0.f, a1 = 0.f, a2 = 0.f, a3 = 0.f;
    float a4 = 0.f, a5 = 0.f, a6 = 0.f, a7 = 0.f;
    #pragma unroll 4
    for (int c8 = 0; c8 < C / 8; ++c8) {
        float4 s0 = *(const float4*)(Srow + c8 * 8);
        float4 s1 = *(const float4*)(Srow + c8 * 8 + 4);
        const float* w = fc_wT + (c8 * 8) * D + d;
        a0 += s0.x * w[0 * D]; a1 += s0.y * w[1 * D];
        a2 += s0.z * w[2 * D]; a3 += s0.w * w[3 * D];
        a4 += s1.x * w[4 * D]; a5 += s1.y * w[5 * D];
        a6 += s1.z * w[6 * D]; a7 += s1.w * w[7 * D];
    }
    Z[((size_t)(g1 * BS + b) * 4 + j) * D + d] =
        ((a0 + a1) + (a2 + a3)) + ((a4 + a5) + (a6 + a7)) + fc_b[d];
}

// K4: attn0 = sigmoid(bd[ch] + Z[g,b,j,:] . Wd[ch,:]) -> A[g1][b][ch][j]
__global__ __launch_bounds__(256) void skatt_attn2(
    const float* __restrict__ Z, const float* __restrict__ Wd,
    const float* __restrict__ bd, float* __restrict__ A)
{
    const int qc = blockIdx.x;
    const int qb = blockIdx.y;
    const int g1 = blockIdx.z;
    const int t  = threadIdx.x;
    const int ch0 = qc * 32, b0 = qb * 32;

    __shared__ float s_z[32 * 4 * 32];
    __shared__ float s_wt[32][32];
    __shared__ float s_bd[32];

    const float* Zs = Z + (size_t)(g1 * BS + b0) * 4 * D;
    #pragma unroll
    for (int i = 0; i < 4; ++i)
        ((float4*)s_z)[t + i * 256] = ((const float4*)Zs)[t + i * 256];
    {
        float4 v = ((const float4*)(Wd + ch0 * D))[t];
        const int ch = t >> 3, d0 = (t & 7) * 4;
        s_wt[d0 + 0][ch] = v.x; s_wt[d0 + 1][ch] = v.y;
        s_wt[d0 + 2][ch] = v.z; s_wt[d0 + 3][ch] = v.w;
    }
    if (t < 32) s_bd[t] = bd[ch0 + t];
    __syncthreads();

    const int ch_l = t & 31, bq = t >> 5;
    float wd[D];
    #pragma unroll
    for (int d = 0; d < D; ++d) wd[d] = s_wt[d][ch_l];
    const float bdv = s_bd[ch_l];

    #pragma unroll
    for (int bi = 0; bi < 4; ++bi) {
        const int b_l = bq + 8 * bi;
        const float* zr = s_z + b_l * 128;
        f32x4 o;
        #pragma unroll
        for (int j = 0; j < 4; ++j) {
            float acc = bdv;
            #pragma unroll
            for (int d = 0; d < D; ++d) acc += zr[j * 32 + d] * wd[d];
            o[j] = 1.0f / (1.0f + __expf(-acc));
        }
        *(f32x4*)(A + ((size_t)(g1 * BS + b0 + b_l) * C + ch0 + ch_l) * 4) = o;
    }
}

// K5: streaming elementwise output, NT stores.
__global__ __launch_bounds__(256) void skatt_out(
    const float* __restrict__ x, const float* __restrict__ x1,
    const float* __restrict__ E, const float* __restrict__ A,
    float* __restrict__ out)
{
    const int q = blockIdx.x;
    const int b = blockIdx.y;
    const int t = threadIdx.x;

    __shared__ float s_A[QCH][12];

    if (t < 96) {
        const int g1 = t >> 5, r = t & 31;
        float4 v = *(const float4*)(A + ((size_t)g1 * BS + b) * (C * 4) + q * (QCH * 4) + r * 4);
        *(float4*)(&s_A[r][g1 * 4]) = v;
    }
    __syncthreads();

    const size_t xbase = (size_t)b * (C * 256);
    const size_t obase = (size_t)b * (C * 192);
    const size_t out2_off = (size_t)BS * C * 192;
    const float* E1 = E;
    const float* E2 = E + (size_t)C * 192;

    #pragma unroll
    for (int i = 0; i < 6; ++i) {
        const int v    = t + i * 256;
        const int ch_l = v / 48;
        const int rem  = v - ch_l * 48;
        const int ch   = q * QCH + ch_l;
        const int j    = rem & 3;
        const int g1   = rem >> 4;

        const float at0 = s_A[ch_l][g1 * 4 + j];
        const float at1 = 1.0f - at0;

        const size_t xofs = xbase + ch * 256 + 64 + rem * 4;
        float4 a  = *(const float4*)(x  + xofs);
        float4 c2 = *(const float4*)(x1 + xofs);
        const size_t eofs = (size_t)ch * 192 + rem * 4;
        float4 e1 = *(const float4*)(E1 + eofs);
        float4 e2 = *(const float4*)(E2 + eofs);

        f32x4 r1, r2;
        r1.x = at0 * a.x + e1.x;   r2.x = at1 * c2.x + e2.x;
        r1.y = at0 * a.y + e1.y;   r2.y = at1 * c2.y + e2.y;
        r1.z = at0 * a.z + e1.z;   r2.z = at1 * c2.z + e2.z;
        r1.w = at0 * a.w + e1.w;   r2.w = at1 * c2.w + e2.w;

        const size_t oofs = obase + ch * 192 + rem * 4;
        __builtin_nontemporal_store(r1, (f32x4*)(out + oofs));
        __builtin_nontemporal_store(r2, (f32x4*)(out + out2_off + oofs));
    }
}

extern "C" void kernel_launch(void* const* d_in, const int* in_sizes, int n_in,
                              void* d_out, int out_size, void* d_ws, size_t ws_size,
                              hipStream_t stream) {
    const float* x     = (const float*)d_in[0];
    const float* x1    = (const float*)d_in[1];
    const float* fc_w  = (const float*)d_in[2];
    const float* fc_b  = (const float*)d_in[3];
    const float* fcs_w = (const float*)d_in[4];
    const float* fcs_b = (const float*)d_in[5];
    float* out = (float*)d_out;

    float* S     = (float*)d_ws;            // 786432 f
    float* A     = S + 786432;              // 786432 f
    float* E     = A + 786432;              // 196608 f
    float* Zb    = E + 196608;              // 49152 f
    float* fc_wT = Zb + 49152;              // 16384 f
    float* Wd    = fc_wT + 16384;           // 16384 f
    float* bd    = Wd + 16384;              // 512 f

    skatt_wprep<<<16,             256, 0, stream>>>(fc_w, fcs_w, fcs_b, fc_wT, Wd, bd);
    skatt_diag <<<dim3(96, 2),    256, 0, stream>>>(x, x1, E);
    skatt_means<<<dim3(3, BS, 4), 256, 0, stream>>>(x, x1, S);
    skatt_z    <<<dim3(3, BS),    128, 0, stream>>>(S, fc_wT, fc_b, Zb);
    skatt_attn2<<<dim3(16, 4, 3), 256, 0, stream>>>(Zb, Wd, bd, A);
    skatt_out  <<<dim3(16, BS),   256, 0, stream>>>(x, x1, E, A, out);
}